// Round 14
// baseline (314.750 us; speedup 1.0000x reference)
//
#include <hip/hip_runtime.h>
#include <hip/hip_bf16.h>

typedef unsigned short u16;
typedef _Float16 f16x8 __attribute__((ext_vector_type(8)));
typedef unsigned short u16x8 __attribute__((ext_vector_type(8)));
typedef float f32x4 __attribute__((ext_vector_type(4)));

#define SQHF 0.70710678118654752440f

__device__ __forceinline__ u16 f2h(float f) {
  const _Float16 h = (_Float16)f;  // RNE
  return __builtin_bit_cast(u16, h);
}

template <int N>
__device__ __forceinline__ void vmwait() {
  asm volatile("s_waitcnt vmcnt(%0)" ::"i"(N) : "memory");
}

// async global->LDS, 16B per lane; LDS dest is wave-uniform base + lane*16
__device__ __forceinline__ void gload_lds16(const void* g, void* l) {
  __builtin_amdgcn_global_load_lds(
      (const __attribute__((address_space(1))) unsigned int*)g,
      (__attribute__((address_space(3))) unsigned int*)l, 16, 0, 0);
}

__device__ __forceinline__ float block_sum(float v) {
#pragma unroll
  for (int o = 32; o; o >>= 1) v += __shfl_xor(v, o);
  __shared__ float red[4];
  if ((threadIdx.x & 63) == 0) red[threadIdx.x >> 6] = v;
  __syncthreads();
  return red[0] + red[1] + red[2] + red[3];
}

// weight-norm of in_v rows (dim E over C), store TRANSPOSED f16 Wt[c][e]
__global__ void wnorm_t_kernel(const float* __restrict__ v, const float* __restrict__ g,
                               u16* __restrict__ wtf) {
  const int e = blockIdx.x;
  const float* vr = v + (long)e * 1024;
  float ss = 0.f;
  for (int c = threadIdx.x; c < 1024; c += 256) { float t = vr[c]; ss += t * t; }
  const float tot = block_sum(ss);
  const float scl = g[e] / sqrtf(tot);
  for (int c = threadIdx.x; c < 1024; c += 256) wtf[(long)c * 1024 + e] = f2h(vr[c] * scl);
}

// weight-norm of out_v rows (dim C over E), natural layout f16 (A for Zo GEMM)
__global__ void wnorm_kernel(const float* __restrict__ v, const float* __restrict__ g,
                             u16* __restrict__ w) {
  const int c = blockIdx.x;
  const float* vr = v + (long)c * 1024;
  float ss = 0.f;
  for (int e = threadIdx.x; e < 1024; e += 256) { float t = vr[e]; ss += t * t; }
  const float tot = block_sum(ss);
  const float scl = g[c] / sqrtf(tot);
  for (int e = threadIdx.x; e < 1024; e += 256) w[(long)c * 1024 + e] = f2h(vr[e] * scl);
}

// conv_feats [B,1024,196] -> y_t f16 into concat cols 1024..2047 (rows v>=196 zero)
// + rc[b][v] += sum_{e in chunk} in_b[e]*y[b,e,v] via f32 atomics (rc pre-zeroed).
__global__ void prep_y_kernel(const float* __restrict__ conv, const float* __restrict__ in_b,
                              u16* __restrict__ concat, float* __restrict__ rc) {
  const int b = blockIdx.x >> 4;
  const int e0 = (blockIdx.x & 15) << 6;
  __shared__ float tile[64 * 224];
  const float* cb = conv + ((long)b * 1024 + e0) * 196;
  for (int idx = threadIdx.x; idx < 64 * 224; idx += 256) {
    const int rr = idx / 224, vv = idx - rr * 224;
    tile[idx] = (vv < 196) ? cb[(long)rr * 196 + vv] : 0.f;
  }
  __syncthreads();
  for (int idx = threadIdx.x; idx < 256 * 64; idx += 256) {
    const int vr = idx >> 6, c = idx & 63;
    const float val = (vr < 224) ? tile[c * 224 + vr] : 0.f;
    concat[((long)b * 256 + vr) * 2048 + 1024 + e0 + c] = f2h(val);
  }
  const int v = threadIdx.x;
  if (v < 196) {
    float s = 0.f;
#pragma unroll 8
    for (int rr = 0; rr < 64; ++rr) s += in_b[e0 + rr] * tile[rr * 224 + v];
    atomicAdd(&rc[b * 256 + v], s);
  }
}

// scores = s0+s1 (K-split halves) +rc, *sqrt(1/2) -> attn f32 [M][196] + attn f16 [M][256]
__global__ void softmax_kernel(const float* __restrict__ s0b, const float* __restrict__ s1b,
                               const float* __restrict__ rc,
                               float* __restrict__ attn, u16* __restrict__ attn_f) {
  const long row = (long)blockIdx.x * 4 + (threadIdx.x >> 6);
  const int lane = threadIdx.x & 63;
  const int b = (int)(row >> 10);
  const float* s0 = s0b + row * 256;
  const float* s1 = s1b + row * 256;
  const float* rcb = rc + b * 256;
  float v0 = (s0[lane] + s1[lane] + rcb[lane]) * SQHF;
  float v1 = (s0[64 + lane] + s1[64 + lane] + rcb[64 + lane]) * SQHF;
  float v2 = (s0[128 + lane] + s1[128 + lane] + rcb[128 + lane]) * SQHF;
  float v3 = (lane < 4) ? (s0[192 + lane] + s1[192 + lane] + rcb[192 + lane]) * SQHF : -1e30f;
  float mx = fmaxf(fmaxf(v0, v1), fmaxf(v2, v3));
#pragma unroll
  for (int o = 32; o; o >>= 1) mx = fmaxf(mx, __shfl_xor(mx, o));
  const float e0 = __expf(v0 - mx), e1 = __expf(v1 - mx), e2 = __expf(v2 - mx);
  const float e3 = (lane < 4) ? __expf(v3 - mx) : 0.f;
  float sm = e0 + e1 + e2 + e3;
#pragma unroll
  for (int o = 32; o; o >>= 1) sm += __shfl_xor(sm, o);
  const float inv = 1.f / sm;
  float* arow = attn + row * 196;
  arow[lane] = e0 * inv;
  arow[64 + lane] = e1 * inv;
  arow[128 + lane] = e2 * inv;
  if (lane < 4) arow[192 + lane] = e3 * inv;
  u16* brow = attn_f + row * 256;
  brow[lane] = f2h(e0 * inv);
  brow[64 + lane] = f2h(e1 * inv);
  brow[128 + lane] = f2h(e2 * inv);
  brow[192 + lane] = (lane < 4) ? f2h(e3 * inv) : (u16)0;
}

// SCORES v2: 128x256 tile, 256 threads (4 waves, wave owns 32 rows x full N).
// R13 post-mortem: staging A through LDS couples the 268MB HBM x/we stream to
// the block barrier (1-block/CU convoy -> 3.1 TB/s). Here A rows are
// WAVE-PRIVATE: loaded f32 global -> named E/O register sets (1-step-ahead
// pipeline, no barrier, no LDS, no ds_write), cvt->f16 at use. Only B (the
// L2-resident concat, 16KB/step) is LDS-staged with the R8-proven counted-
// vmcnt dbuf: per iter {issueA(t+1); stageB(cur^1,t+1); vmcnt(8); barrier;
// compute; barrier}. vmcnt(8) = A(t+1)4 + B(t+1)4 in flight, retires A(t),B(t).
// LDS 32KB, ~190 VGPR -> 2 blocks/CU resident. grid = 2 halves x 256 mTiles.
__global__ __launch_bounds__(256) void gemm_scores2(
    const float* __restrict__ x, const float* __restrict__ we,
    const u16* __restrict__ Bh,
    float* __restrict__ out0, float* __restrict__ out1) {
  constexpr int HSM = 8192;  // per-buffer u16 slots (16KB): 256 rows x 32
  __shared__ __align__(16) u16 smem[HSM * 2];

  int bid = blockIdx.x;
  const int half = bid & 1;
  bid >>= 1;
  const int nwg = gridDim.x >> 1;            // 256
  const int q = nwg >> 3, xcd = bid & 7, l8 = bid >> 3;
  const int mTile = xcd * q + l8;            // bijective (nwg%8==0)
  const long rowBase = (long)mTile << 7;
  const int kOff = half << 10;               // B column offset (Zi | y)

  const u16* Bg = Bh + (long)(mTile >> 3) * 524288l;  // batch b = mTile/8
  const float* Ab = half ? we : x;

  const int tid = threadIdx.x;
  const int wave = tid >> 6, lane = tid & 63;
  const int lr = lane & 15;
  const int lk8 = (lane >> 4) << 3;          // A k-chunk (f32 elems)

  const float* Ar0 = Ab + (rowBase + wave * 32 + lr) * 1024l + lk8;
  const float* Ar1 = Ar0 + 16 * 1024l;

  const int sr_ = lane >> 2;                 // B staging row within 64-group
  const int sc_ = lane & 3;

  f32x4 acc[2][16];
#pragma unroll
  for (int m = 0; m < 2; ++m)
#pragma unroll
    for (int n = 0; n < 16; ++n) acc[m][n] = f32x4{0.f, 0.f, 0.f, 0.f};

  // E/O named A register sets (rule #20: static naming, no runtime index)
  f32x4 aE0, aE1, aE2, aE3, aO0, aO1, aO2, aO3;

  auto stageB = [&](int buf, int k0) {
    u16* sb = smem + buf * HSM;
#pragma unroll
    for (int i = 0; i < 4; ++i) {
      const int r = i * 64 + wave * 16 + sr_;
      const int csw = ((sc_ ^ ((r >> 1) & 3)) << 3);       // chunk-XOR swizzled src
      gload_lds16(Bg + (long)r * 2048 + k0 + kOff + csw,
                  &sb[(i * 256 + wave * 64) * 8]);         // linear LDS dest
    }
  };
  auto issueE = [&](int k0) {
    const float* p0 = Ar0 + k0;
    const float* p1 = Ar1 + k0;
    aE0 = *(const f32x4*)p0; aE1 = *(const f32x4*)(p0 + 4);
    aE2 = *(const f32x4*)p1; aE3 = *(const f32x4*)(p1 + 4);
  };
  auto issueO = [&](int k0) {
    const float* p0 = Ar0 + k0;
    const float* p1 = Ar1 + k0;
    aO0 = *(const f32x4*)p0; aO1 = *(const f32x4*)(p0 + 4);
    aO2 = *(const f32x4*)p1; aO3 = *(const f32x4*)(p1 + 4);
  };

  auto computeS = [&](int buf, const f32x4& a0, const f32x4& a1,
                      const f32x4& a2, const f32x4& a3) {
    const u16* sb = smem + buf * HSM;
    f16x8 fa0, fa1;
    fa0[0] = (_Float16)a0[0]; fa0[1] = (_Float16)a0[1];
    fa0[2] = (_Float16)a0[2]; fa0[3] = (_Float16)a0[3];
    fa0[4] = (_Float16)a1[0]; fa0[5] = (_Float16)a1[1];
    fa0[6] = (_Float16)a1[2]; fa0[7] = (_Float16)a1[3];
    fa1[0] = (_Float16)a2[0]; fa1[1] = (_Float16)a2[1];
    fa1[2] = (_Float16)a2[2]; fa1[3] = (_Float16)a2[3];
    fa1[4] = (_Float16)a3[0]; fa1[5] = (_Float16)a3[1];
    fa1[6] = (_Float16)a3[2]; fa1[7] = (_Float16)a3[3];
    __builtin_amdgcn_s_setprio(1);
#pragma unroll
    for (int n = 0; n < 16; ++n) {
      const int v = n * 16 + lr;
      const int off = v * 32 + (((lane >> 4) ^ ((v >> 1) & 3)) << 3);
      const f16x8 fb = __builtin_bit_cast(f16x8, *(const u16x8*)&sb[off]);
      acc[0][n] = __builtin_amdgcn_mfma_f32_16x16x32_f16(fa0, fb, acc[0][n], 0, 0, 0);
      acc[1][n] = __builtin_amdgcn_mfma_f32_16x16x32_f16(fa1, fb, acc[1][n], 0, 0, 0);
    }
    __builtin_amdgcn_s_setprio(0);
  };

  // prologue: A(0)->E, B(0)->buf0
  issueE(0);
  stageB(0, 0);
  for (int t = 0; t < 32; t += 2) {
    // iter t (even): compute set E, buf0; prefetch t+1 into O/buf1
    issueO((t + 1) << 5);
    stageB(1, (t + 1) << 5);
    vmwait<8>();                             // A(t),B(t) retired; t+1 in flight
    __builtin_amdgcn_s_barrier();
    __builtin_amdgcn_sched_barrier(0);
    computeS(0, aE0, aE1, aE2, aE3);
    __builtin_amdgcn_sched_barrier(0);
    __builtin_amdgcn_s_barrier();
    // iter t+1 (odd): compute set O, buf1; prefetch t+2 into E/buf0
    if (t + 2 < 32) {
      issueE((t + 2) << 5);
      stageB(0, (t + 2) << 5);
      vmwait<8>();
    } else {
      vmwait<0>();
    }
    __builtin_amdgcn_s_barrier();
    __builtin_amdgcn_sched_barrier(0);
    computeS(1, aO0, aO1, aO2, aO3);
    __builtin_amdgcn_sched_barrier(0);
    __builtin_amdgcn_s_barrier();
  }

  float* o = half ? out1 : out0;
  const int rloc = (lane >> 4) << 2;
#pragma unroll
  for (int m = 0; m < 2; ++m)
#pragma unroll
    for (int n = 0; n < 16; ++n)
#pragma unroll
      for (int j = 0; j < 4; ++j) {
        const long row = rowBase + wave * 32 + m * 16 + rloc + j;
        o[row * 256 + n * 16 + lr] = acc[m][n][j];
      }
}

// 128x128-tile fp16 MFMA GEMM, B^T-layout operands, T4 counted-vmcnt
// pipeline (R8-validated). A,B f16 via global_load_lds; 4 loads/stage; 32KB LDS.
// f16 LDS tiles use chunk-XOR swizzle (row>>1)&3 on both stage-src and read.
// EPI: 1=(acc+bias[col]+extra[row*ldOut+col])*scale -> f32
//      6=(_Float16)(acc*scale) -> f16
// NOTE: NO min-waves clause (R3: (256,4)->spills; R4: (256,2)->lost ILP).
template <int EPI>
__global__ __launch_bounds__(256) void gemm128(
    const u16* __restrict__ Ah, const u16* __restrict__ Bh,
    int N, int K, int ldA, int ldB, int ldOut,
    int mTilesPerBatch, long bStride, int aTilesMod,
    const float* __restrict__ bias, const float* __restrict__ extra,
    float scale, void* __restrict__ out1) {
  constexpr int TBH = 4096;
  constexpr int HSM = 8192;
  __shared__ __align__(16) u16 smem[HSM * 2];

  const int bid = blockIdx.x, nwg = gridDim.x;
  const int numN = N >> 7;
  const int q = nwg >> 3, r = nwg & 7, xcd = bid & 7, l8 = bid >> 3;
  const int wg = (xcd < r ? xcd * (q + 1) : r * (q + 1) + (xcd - r) * q) + l8;
  const int mTile = wg / numN, nTile = wg - mTile * numN;
  const long rowBase = (long)mTile << 7;
  const int colBase = nTile << 7;
  const int aTile = aTilesMod ? (mTile % aTilesMod) : mTile;
  const long aRowBase = (long)aTile << 7;
  const long bOff = mTilesPerBatch ? (long)(mTile / mTilesPerBatch) * bStride : 0;

  const u16* Agh = Ah + aRowBase * ldA;
  const u16* Bgh = Bh + bOff + (long)colBase * ldB;

  const int tid = threadIdx.x;
  const int wave = tid >> 6, lane = tid & 63;
  const int wr = wave >> 1, wc = wave & 1;
  const int sr = wave * 16 + (lane >> 2);
  const int scS = (((lane & 3) ^ ((sr >> 1) & 3)) << 3);
  const int lr = lane & 15;

  f32x4 acc[4][4];
#pragma unroll
  for (int m = 0; m < 4; ++m)
#pragma unroll
    for (int n = 0; n < 4; ++n) acc[m][n] = f32x4{0.f, 0.f, 0.f, 0.f};

  auto stage = [&](int buf, int k0) {
    u16* sb = smem + buf * HSM;
#pragma unroll
    for (int i = 0; i < 2; ++i) {
      const long roA = (long)(i * 64 + sr) * ldA + k0 + scS;
      const long roB = (long)(i * 64 + sr) * ldB + k0 + scS;
      const int lo_ = i * 2048 + wave * 512;
      gload_lds16(Agh + roA, &sb[lo_]);
      gload_lds16(Bgh + roB, &sb[TBH + lo_]);
    }
  };

  auto compute = [&](int buf) {
    const u16* sb = smem + buf * HSM;
    f16x8 fa[4], fb[4];
#pragma unroll
    for (int m = 0; m < 4; ++m) {
      const int row = wr * 64 + m * 16 + lr;
      const int off = row * 32 + (((lane >> 4) ^ ((row >> 1) & 3)) << 3);
      fa[m] = __builtin_bit_cast(f16x8, *(const u16x8*)&sb[off]);
    }
#pragma unroll
    for (int n = 0; n < 4; ++n) {
      const int row = wc * 64 + n * 16 + lr;
      const int off = row * 32 + (((lane >> 4) ^ ((row >> 1) & 3)) << 3);
      fb[n] = __builtin_bit_cast(f16x8, *(const u16x8*)&sb[TBH + off]);
    }
    __builtin_amdgcn_s_setprio(1);
#pragma unroll
    for (int m = 0; m < 4; ++m)
#pragma unroll
      for (int n = 0; n < 4; ++n)
        acc[m][n] = __builtin_amdgcn_mfma_f32_16x16x32_f16(fa[m], fb[n], acc[m][n], 0, 0, 0);
    __builtin_amdgcn_s_setprio(0);
  };

  const int nSteps = K >> 5;
  stage(0, 0);
  for (int t = 0; t < nSteps; ++t) {
    const int cur = t & 1;
    if (t + 1 < nSteps) {
      stage(cur ^ 1, (t + 1) << 5);
      vmwait<4>();
    } else {
      vmwait<0>();
    }
    __builtin_amdgcn_s_barrier();
    __builtin_amdgcn_sched_barrier(0);
    compute(cur);
    __builtin_amdgcn_sched_barrier(0);
    __builtin_amdgcn_s_barrier();
  }

  const int rloc = (lane >> 4) << 2;
#pragma unroll
  for (int m = 0; m < 4; ++m) {
#pragma unroll
    for (int n = 0; n < 4; ++n) {
      const int col = colBase + wc * 64 + n * 16 + lr;
#pragma unroll
      for (int j = 0; j < 4; ++j) {
        const long row = rowBase + wr * 64 + m * 16 + rloc + j;
        const float v = acc[m][n][j];
        if (EPI == 1) {
          ((float*)out1)[row * (long)ldOut + col] =
              (v + bias[col] + extra[row * (long)ldOut + col]) * scale;
        } else if (EPI == 6) {
          ((u16*)out1)[row * (long)ldOut + col] = f2h(v * scale);
        }
      }
    }
  }
}

extern "C" void kernel_launch(void* const* d_in, const int* in_sizes, int n_in,
                              void* d_out, int out_size, void* d_ws, size_t ws_size,
                              hipStream_t stream) {
  (void)in_sizes; (void)n_in; (void)out_size; (void)ws_size;
  const float* x     = (const float*)d_in[0];
  const float* we    = (const float*)d_in[1];
  const float* conv  = (const float*)d_in[2];
  const float* in_v  = (const float*)d_in[3];
  const float* in_g  = (const float*)d_in[4];
  const float* in_b  = (const float*)d_in[5];
  const float* out_v = (const float*)d_in[6];
  const float* out_g = (const float*)d_in[7];
  const float* out_b = (const float*)d_in[8];
  float* out  = (float*)d_out;
  float* attn = out + 33554432l;  // B*L*C floats, then B*L*196

  char* ws = (char*)d_ws;
  u16* concat = (u16*)(ws);                  // f16 [32][256][2048]: cols 0..1023 Zi | 1024.. y
  u16* wtf    = (u16*)(ws + 33554432l);      // Wt f16 [1024][1024] (transposed Wi)
  u16* wo     = (u16*)(ws + 35651584l);      // Wo f16 [1024][1024]
  u16* zo     = (u16*)(ws + 37748736l);      // Zo f16 [32][1024][256] (x14 folded)
  u16* attf   = (u16*)(ws + 54525952l);      // attn f16 [32768][256]
  float* rc   = (float*)(ws + 71303168l);    // [32][256]
  float* s1   = (float*)(ws + 71368704l);    // K-split half-1 scores [32768][256]
  float* s0   = out;                         // K-split half-0 scores in out region

  hipMemsetAsync(rc, 0, 32 * 256 * sizeof(float), stream);
  wnorm_t_kernel<<<1024, 256, 0, stream>>>(in_v, in_g, wtf);
  wnorm_kernel<<<1024, 256, 0, stream>>>(out_v, out_g, wo);
  prep_y_kernel<<<512, 256, 0, stream>>>(conv, in_b, concat, rc);
  // Zi^T[b*256+v][c] = sum_e y[b][v][e] * Wt[c][e], single-f16 MFMA,
  // A = y half of concat, out f16 into concat cols 0..1023 (M=8192,N=1024,K=1024)
  gemm128<6><<<512, 256, 0, stream>>>(
      concat + 1024, wtf, 1024, 1024, 2048, 1024, 2048,
      0, 0, 0, nullptr, nullptr, 1.f, concat);
  // scores = [x|we] @ [Zi;y], wave-private-A kernel (grid 2x256):
  // half0: x@Zi -> s0 ; half1: we@y -> s1
  gemm_scores2<<<512, 256, 0, stream>>>(x, we, concat, s0, s1);
  softmax_kernel<<<8192, 256, 0, stream>>>(s0, s1, rc, attn, attf);
  // Zo[b*1024+c][v] = 14 * sum_e Wo[c][e] * y[b][v][e] -> f16
  // (M=32768,N=256,K=1024; A=Wo replicated per batch, B=y half of concat batched)
  gemm128<6><<<512, 256, 0, stream>>>(
      wo, concat + 1024, 256, 1024, 1024, 2048, 256,
      8, 524288l, 8, nullptr, nullptr, 14.f, zo);
  // out = (attf @ Zo^T + out_b + x) * sqrt(0.5)  (M=32768, N=1024, K=256)
  gemm128<1><<<2048, 256, 0, stream>>>(
      attf, zo, 1024, 256, 256, 256, 1024,
      8, 262144l, 0, out_b, x, SQHF, out);
}

// Round 15
// 305.419 us; speedup vs baseline: 1.0306x; 1.0306x over previous
//
#include <hip/hip_runtime.h>
#include <hip/hip_bf16.h>

typedef unsigned short u16;
typedef _Float16 f16x8 __attribute__((ext_vector_type(8)));
typedef unsigned short u16x8 __attribute__((ext_vector_type(8)));
typedef float f32x4 __attribute__((ext_vector_type(4)));

#define SQHF 0.70710678118654752440f

__device__ __forceinline__ u16 f2h(float f) {
  const _Float16 h = (_Float16)f;  // RNE
  return __builtin_bit_cast(u16, h);
}

template <int N>
__device__ __forceinline__ void vmwait() {
  asm volatile("s_waitcnt vmcnt(%0)" ::"i"(N) : "memory");
}

// async global->LDS, 16B per lane; LDS dest is wave-uniform base + lane*16
__device__ __forceinline__ void gload_lds16(const void* g, void* l) {
  __builtin_amdgcn_global_load_lds(
      (const __attribute__((address_space(1))) unsigned int*)g,
      (__attribute__((address_space(3))) unsigned int*)l, 16, 0, 0);
}

__device__ __forceinline__ float block_sum(float v) {
#pragma unroll
  for (int o = 32; o; o >>= 1) v += __shfl_xor(v, o);
  __shared__ float red[4];
  if ((threadIdx.x & 63) == 0) red[threadIdx.x >> 6] = v;
  __syncthreads();
  return red[0] + red[1] + red[2] + red[3];
}

// weight-norm of in_v rows (dim E over C), store TRANSPOSED f16 Wt[c][e]
__global__ void wnorm_t_kernel(const float* __restrict__ v, const float* __restrict__ g,
                               u16* __restrict__ wtf) {
  const int e = blockIdx.x;
  const float* vr = v + (long)e * 1024;
  float ss = 0.f;
  for (int c = threadIdx.x; c < 1024; c += 256) { float t = vr[c]; ss += t * t; }
  const float tot = block_sum(ss);
  const float scl = g[e] / sqrtf(tot);
  for (int c = threadIdx.x; c < 1024; c += 256) wtf[(long)c * 1024 + e] = f2h(vr[c] * scl);
}

// weight-norm of out_v rows (dim C over E), natural layout f16 (A for Zo GEMM)
__global__ void wnorm_kernel(const float* __restrict__ v, const float* __restrict__ g,
                             u16* __restrict__ w) {
  const int c = blockIdx.x;
  const float* vr = v + (long)c * 1024;
  float ss = 0.f;
  for (int e = threadIdx.x; e < 1024; e += 256) { float t = vr[e]; ss += t * t; }
  const float tot = block_sum(ss);
  const float scl = g[c] / sqrtf(tot);
  for (int e = threadIdx.x; e < 1024; e += 256) w[(long)c * 1024 + e] = f2h(vr[e] * scl);
}

// conv_feats [B,1024,196] -> y_t f16 into concat cols 1024..2047 (rows v>=196 zero)
// + rc[b][v] += sum_{e in chunk} in_b[e]*y[b,e,v] via f32 atomics (rc pre-zeroed).
__global__ void prep_y_kernel(const float* __restrict__ conv, const float* __restrict__ in_b,
                              u16* __restrict__ concat, float* __restrict__ rc) {
  const int b = blockIdx.x >> 4;
  const int e0 = (blockIdx.x & 15) << 6;
  __shared__ float tile[64 * 224];
  const float* cb = conv + ((long)b * 1024 + e0) * 196;
  for (int idx = threadIdx.x; idx < 64 * 224; idx += 256) {
    const int rr = idx / 224, vv = idx - rr * 224;
    tile[idx] = (vv < 196) ? cb[(long)rr * 196 + vv] : 0.f;
  }
  __syncthreads();
  for (int idx = threadIdx.x; idx < 256 * 64; idx += 256) {
    const int vr = idx >> 6, c = idx & 63;
    const float val = (vr < 224) ? tile[c * 224 + vr] : 0.f;
    concat[((long)b * 256 + vr) * 2048 + 1024 + e0 + c] = f2h(val);
  }
  const int v = threadIdx.x;
  if (v < 196) {
    float s = 0.f;
#pragma unroll 8
    for (int rr = 0; rr < 64; ++rr) s += in_b[e0 + rr] * tile[rr * 224 + v];
    atomicAdd(&rc[b * 256 + v], s);
  }
}

// scores = s0+s1 (K-split halves) +rc, *sqrt(1/2) -> attn f32 [M][196] + attn f16 [M][256]
__global__ void softmax_kernel(const float* __restrict__ s0b, const float* __restrict__ s1b,
                               const float* __restrict__ rc,
                               float* __restrict__ attn, u16* __restrict__ attn_f) {
  const long row = (long)blockIdx.x * 4 + (threadIdx.x >> 6);
  const int lane = threadIdx.x & 63;
  const int b = (int)(row >> 10);
  const float* s0 = s0b + row * 256;
  const float* s1 = s1b + row * 256;
  const float* rcb = rc + b * 256;
  float v0 = (s0[lane] + s1[lane] + rcb[lane]) * SQHF;
  float v1 = (s0[64 + lane] + s1[64 + lane] + rcb[64 + lane]) * SQHF;
  float v2 = (s0[128 + lane] + s1[128 + lane] + rcb[128 + lane]) * SQHF;
  float v3 = (lane < 4) ? (s0[192 + lane] + s1[192 + lane] + rcb[192 + lane]) * SQHF : -1e30f;
  float mx = fmaxf(fmaxf(v0, v1), fmaxf(v2, v3));
#pragma unroll
  for (int o = 32; o; o >>= 1) mx = fmaxf(mx, __shfl_xor(mx, o));
  const float e0 = __expf(v0 - mx), e1 = __expf(v1 - mx), e2 = __expf(v2 - mx);
  const float e3 = (lane < 4) ? __expf(v3 - mx) : 0.f;
  float sm = e0 + e1 + e2 + e3;
#pragma unroll
  for (int o = 32; o; o >>= 1) sm += __shfl_xor(sm, o);
  const float inv = 1.f / sm;
  float* arow = attn + row * 196;
  arow[lane] = e0 * inv;
  arow[64 + lane] = e1 * inv;
  arow[128 + lane] = e2 * inv;
  if (lane < 4) arow[192 + lane] = e3 * inv;
  u16* brow = attn_f + row * 256;
  brow[lane] = f2h(e0 * inv);
  brow[64 + lane] = f2h(e1 * inv);
  brow[128 + lane] = f2h(e2 * inv);
  brow[192 + lane] = (lane < 4) ? f2h(e3 * inv) : (u16)0;
}

// SCORES (exact R8-proven structure, dedicated kernel): 128x128 tile, 256 thr,
// kSplit2 grid 2x512=1024 blocks. A staged as f32 (XOR-swizzled) into LDS via
// global_load_lds, cvt->f16 in-register at fragment load; B f16 (concat) via
// global_load_lds with chunk-XOR swizzled source. 24KB/buf x2 = 48KB LDS,
// ~68 VGPR -> 3-4 blocks/CU resident. Counted-vmcnt pipeline: per step
// {stage(next)[LPS=6]; vmcnt(6); s_barrier; compute; s_barrier}.
// R14 post-mortem: byte-cutting variants (numN=1 / wave-private A) all lost
// residency (LDS or VGPR) and delivered 3-4 TB/s vs this structure's 7.1;
// R8's config is the empirical optimum of the bytes-vs-residency trade.
__global__ __launch_bounds__(256) void gemm_scores_r8(
    const float* __restrict__ x, const float* __restrict__ we,
    const u16* __restrict__ Bh,
    float* __restrict__ out0, float* __restrict__ out1) {
  constexpr int TBH = 8192;    // B tile base (u16 slots); A f32 tile = slots 0..8191
  constexpr int HSM = 12288;   // per-buffer u16 slots (24KB)
  __shared__ __align__(16) u16 smem[HSM * 2];

  int bid = blockIdx.x;
  const int half = bid & 1;
  bid >>= 1;
  const int nwg = gridDim.x >> 1;            // 512
  const int q = nwg >> 3, xcd = bid & 7, l8 = bid >> 3;
  const int wg = xcd * q + l8;               // bijective (nwg%8==0)
  const int mTile = wg >> 1, nTile = wg & 1; // numN=2 (n-pair same XCD chunk)
  const long rowBase = (long)mTile << 7;
  const int colBase = nTile << 7;
  const int kOff = half << 10;

  const float* Ab = half ? we : x;
  const float* Ag = Ab + rowBase * 1024;
  const u16* Bg = Bh + (long)(mTile >> 3) * 524288l + (long)colBase * 2048;

  const int tid = threadIdx.x;
  const int wave = tid >> 6, lane = tid & 63;
  const int wr = wave >> 1, wc = wave & 1;
  const int sr = wave * 16 + (lane >> 2);
  const int scS = (((lane & 3) ^ ((sr >> 1) & 3)) << 3);
  const int lr = lane & 15;
  const int lk = (lane >> 4) << 3;

  f32x4 acc[4][4];
#pragma unroll
  for (int m = 0; m < 4; ++m)
#pragma unroll
    for (int n = 0; n < 4; ++n) acc[m][n] = f32x4{0.f, 0.f, 0.f, 0.f};

  auto stage = [&](int buf, int k0) {
    u16* sb = smem + buf * HSM;
    const float* As = Ag + k0;
    const int rr = tid >> 3;
#pragma unroll
    for (int i = 0; i < 4; ++i) {            // A: 128 rows x 32 f32
      const int row = i * 32 + rr;
      const int csw = (((tid & 7) ^ (row & 7)) << 2);  // XOR-swizzled f32 col
      gload_lds16(As + (long)row * 1024 + csw, &sb[i * 2048 + wave * 512]);
    }
#pragma unroll
    for (int i = 0; i < 2; ++i) {            // B: 128 rows x 32 f16
      const long ro = (long)(i * 64 + sr) * 2048 + k0 + kOff + scS;
      gload_lds16(Bg + ro, &sb[TBH + i * 2048 + wave * 512]);
    }
  };

  auto compute = [&](int buf) {
    const u16* sb = smem + buf * HSM;
    f16x8 fa[4], fb[4];
    const char* smemb = (const char*)sb;
#pragma unroll
    for (int m = 0; m < 4; ++m) {
      const int row = wr * 64 + m * 16 + lr;
      const int xr = (row & 7) << 4;
      const char* rp = smemb + row * 128;
      const f32x4 p0 = *(const f32x4*)(rp + ((lk << 2) ^ xr));
      const f32x4 p1 = *(const f32x4*)(rp + (((lk << 2) + 16) ^ xr));
      f16x8 va;
      va[0] = (_Float16)p0.x; va[1] = (_Float16)p0.y;
      va[2] = (_Float16)p0.z; va[3] = (_Float16)p0.w;
      va[4] = (_Float16)p1.x; va[5] = (_Float16)p1.y;
      va[6] = (_Float16)p1.z; va[7] = (_Float16)p1.w;
      fa[m] = va;
    }
#pragma unroll
    for (int n = 0; n < 4; ++n) {
      const int row = wc * 64 + n * 16 + lr;
      const int off = TBH + row * 32 + (((lane >> 4) ^ ((row >> 1) & 3)) << 3);
      fb[n] = __builtin_bit_cast(f16x8, *(const u16x8*)&sb[off]);
    }
    __builtin_amdgcn_s_setprio(1);
#pragma unroll
    for (int m = 0; m < 4; ++m)
#pragma unroll
      for (int n = 0; n < 4; ++n)
        acc[m][n] = __builtin_amdgcn_mfma_f32_16x16x32_f16(fa[m], fb[n], acc[m][n], 0, 0, 0);
    __builtin_amdgcn_s_setprio(0);
  };

  // T4 counted-vmcnt pipeline, 2 buffers, 2 raw barriers/iter, LPS=6.
  stage(0, 0);
  for (int t = 0; t < 32; ++t) {
    const int cur = t & 1;
    if (t + 1 < 32) {
      stage(cur ^ 1, (t + 1) << 5);
      vmwait<6>();
    } else {
      vmwait<0>();
    }
    __builtin_amdgcn_s_barrier();
    __builtin_amdgcn_sched_barrier(0);
    compute(cur);
    __builtin_amdgcn_sched_barrier(0);
    __builtin_amdgcn_s_barrier();
  }

  float* o = half ? out1 : out0;
  const int rloc = (lane >> 4) << 2;
#pragma unroll
  for (int m = 0; m < 4; ++m)
#pragma unroll
    for (int n = 0; n < 4; ++n) {
      const int col = colBase + wc * 64 + n * 16 + lr;
#pragma unroll
      for (int j = 0; j < 4; ++j) {
        const long row = rowBase + wr * 64 + m * 16 + rloc + j;
        o[row * 256 + col] = acc[m][n][j];
      }
    }
}

// 128x128-tile fp16 MFMA GEMM, B^T-layout operands, T4 counted-vmcnt
// pipeline (R8-validated). A,B f16 via global_load_lds; 4 loads/stage; 32KB LDS.
// f16 LDS tiles use chunk-XOR swizzle (row>>1)&3 on both stage-src and read.
// EPI: 1=(acc+bias[col]+extra[row*ldOut+col])*scale -> f32
//      6=(_Float16)(acc*scale) -> f16
// NOTE: NO min-waves clause (R3: (256,4)->spills; R4: (256,2)->lost ILP).
template <int EPI>
__global__ __launch_bounds__(256) void gemm128(
    const u16* __restrict__ Ah, const u16* __restrict__ Bh,
    int N, int K, int ldA, int ldB, int ldOut,
    int mTilesPerBatch, long bStride, int aTilesMod,
    const float* __restrict__ bias, const float* __restrict__ extra,
    float scale, void* __restrict__ out1) {
  constexpr int TBH = 4096;
  constexpr int HSM = 8192;
  __shared__ __align__(16) u16 smem[HSM * 2];

  const int bid = blockIdx.x, nwg = gridDim.x;
  const int numN = N >> 7;
  const int q = nwg >> 3, r = nwg & 7, xcd = bid & 7, l8 = bid >> 3;
  const int wg = (xcd < r ? xcd * (q + 1) : r * (q + 1) + (xcd - r) * q) + l8;
  const int mTile = wg / numN, nTile = wg - mTile * numN;
  const long rowBase = (long)mTile << 7;
  const int colBase = nTile << 7;
  const int aTile = aTilesMod ? (mTile % aTilesMod) : mTile;
  const long aRowBase = (long)aTile << 7;
  const long bOff = mTilesPerBatch ? (long)(mTile / mTilesPerBatch) * bStride : 0;

  const u16* Agh = Ah + aRowBase * ldA;
  const u16* Bgh = Bh + bOff + (long)colBase * ldB;

  const int tid = threadIdx.x;
  const int wave = tid >> 6, lane = tid & 63;
  const int wr = wave >> 1, wc = wave & 1;
  const int sr = wave * 16 + (lane >> 2);
  const int scS = (((lane & 3) ^ ((sr >> 1) & 3)) << 3);
  const int lr = lane & 15;

  f32x4 acc[4][4];
#pragma unroll
  for (int m = 0; m < 4; ++m)
#pragma unroll
    for (int n = 0; n < 4; ++n) acc[m][n] = f32x4{0.f, 0.f, 0.f, 0.f};

  auto stage = [&](int buf, int k0) {
    u16* sb = smem + buf * HSM;
#pragma unroll
    for (int i = 0; i < 2; ++i) {
      const long roA = (long)(i * 64 + sr) * ldA + k0 + scS;
      const long roB = (long)(i * 64 + sr) * ldB + k0 + scS;
      const int lo_ = i * 2048 + wave * 512;
      gload_lds16(Agh + roA, &sb[lo_]);
      gload_lds16(Bgh + roB, &sb[TBH + lo_]);
    }
  };

  auto compute = [&](int buf) {
    const u16* sb = smem + buf * HSM;
    f16x8 fa[4], fb[4];
#pragma unroll
    for (int m = 0; m < 4; ++m) {
      const int row = wr * 64 + m * 16 + lr;
      const int off = row * 32 + (((lane >> 4) ^ ((row >> 1) & 3)) << 3);
      fa[m] = __builtin_bit_cast(f16x8, *(const u16x8*)&sb[off]);
    }
#pragma unroll
    for (int n = 0; n < 4; ++n) {
      const int row = wc * 64 + n * 16 + lr;
      const int off = row * 32 + (((lane >> 4) ^ ((row >> 1) & 3)) << 3);
      fb[n] = __builtin_bit_cast(f16x8, *(const u16x8*)&sb[TBH + off]);
    }
    __builtin_amdgcn_s_setprio(1);
#pragma unroll
    for (int m = 0; m < 4; ++m)
#pragma unroll
      for (int n = 0; n < 4; ++n)
        acc[m][n] = __builtin_amdgcn_mfma_f32_16x16x32_f16(fa[m], fb[n], acc[m][n], 0, 0, 0);
    __builtin_amdgcn_s_setprio(0);
  };

  const int nSteps = K >> 5;
  stage(0, 0);
  for (int t = 0; t < nSteps; ++t) {
    const int cur = t & 1;
    if (t + 1 < nSteps) {
      stage(cur ^ 1, (t + 1) << 5);
      vmwait<4>();
    } else {
      vmwait<0>();
    }
    __builtin_amdgcn_s_barrier();
    __builtin_amdgcn_sched_barrier(0);
    compute(cur);
    __builtin_amdgcn_sched_barrier(0);
    __builtin_amdgcn_s_barrier();
  }

  const int rloc = (lane >> 4) << 2;
#pragma unroll
  for (int m = 0; m < 4; ++m) {
#pragma unroll
    for (int n = 0; n < 4; ++n) {
      const int col = colBase + wc * 64 + n * 16 + lr;
#pragma unroll
      for (int j = 0; j < 4; ++j) {
        const long row = rowBase + wr * 64 + m * 16 + rloc + j;
        const float v = acc[m][n][j];
        if (EPI == 1) {
          ((float*)out1)[row * (long)ldOut + col] =
              (v + bias[col] + extra[row * (long)ldOut + col]) * scale;
        } else if (EPI == 6) {
          ((u16*)out1)[row * (long)ldOut + col] = f2h(v * scale);
        }
      }
    }
  }
}

extern "C" void kernel_launch(void* const* d_in, const int* in_sizes, int n_in,
                              void* d_out, int out_size, void* d_ws, size_t ws_size,
                              hipStream_t stream) {
  (void)in_sizes; (void)n_in; (void)out_size; (void)ws_size;
  const float* x     = (const float*)d_in[0];
  const float* we    = (const float*)d_in[1];
  const float* conv  = (const float*)d_in[2];
  const float* in_v  = (const float*)d_in[3];
  const float* in_g  = (const float*)d_in[4];
  const float* in_b  = (const float*)d_in[5];
  const float* out_v = (const float*)d_in[6];
  const float* out_g = (const float*)d_in[7];
  const float* out_b = (const float*)d_in[8];
  float* out  = (float*)d_out;
  float* attn = out + 33554432l;  // B*L*C floats, then B*L*196

  char* ws = (char*)d_ws;
  u16* concat = (u16*)(ws);                  // f16 [32][256][2048]: cols 0..1023 Zi | 1024.. y
  u16* wtf    = (u16*)(ws + 33554432l);      // Wt f16 [1024][1024] (transposed Wi)
  u16* wo     = (u16*)(ws + 35651584l);      // Wo f16 [1024][1024]
  u16* zo     = (u16*)(ws + 37748736l);      // Zo f16 [32][1024][256] (x14 folded)
  u16* attf   = (u16*)(ws + 54525952l);      // attn f16 [32768][256]
  float* rc   = (float*)(ws + 71303168l);    // [32][256]
  float* s1   = (float*)(ws + 71368704l);    // K-split half-1 scores [32768][256]
  float* s0   = out;                         // K-split half-0 scores in out region

  hipMemsetAsync(rc, 0, 32 * 256 * sizeof(float), stream);
  wnorm_t_kernel<<<1024, 256, 0, stream>>>(in_v, in_g, wtf);
  wnorm_kernel<<<1024, 256, 0, stream>>>(out_v, out_g, wo);
  prep_y_kernel<<<512, 256, 0, stream>>>(conv, in_b, concat, rc);
  // Zi^T[b*256+v][c] = sum_e y[b][v][e] * Wt[c][e], single-f16 MFMA,
  // A = y half of concat, out f16 into concat cols 0..1023 (M=8192,N=1024,K=1024)
  gemm128<6><<<512, 256, 0, stream>>>(
      concat + 1024, wtf, 1024, 1024, 2048, 1024, 2048,
      0, 0, 0, nullptr, nullptr, 1.f, concat);
  // scores = [x|we] @ [Zi;y], R8-proven 128x128 structure (grid 2x512):
  // half0: x@Zi -> s0 ; half1: we@y -> s1
  gemm_scores_r8<<<1024, 256, 0, stream>>>(x, we, concat, s0, s1);
  softmax_kernel<<<8192, 256, 0, stream>>>(s0, s1, rc, attn, attf);
  // Zo[b*1024+c][v] = 14 * sum_e Wo[c][e] * y[b][v][e] -> f16
  // (M=32768,N=256,K=1024; A=Wo replicated per batch, B=y half of concat batched)
  gemm128<6><<<512, 256, 0, stream>>>(
      wo, concat + 1024, 256, 1024, 1024, 2048, 256,
      8, 524288l, 8, nullptr, nullptr, 14.f, zo);
  // out = (attf @ Zo^T + out_b + x) * sqrt(0.5)  (M=32768, N=1024, K=256)
  gemm128<1><<<2048, 256, 0, stream>>>(
      attf, zo, 1024, 256, 256, 256, 1024,
      8, 262144l, 0, out_b, x, SQHF, out);
}